// Round 1
// baseline (2405.971 us; speedup 1.0000x reference)
//
#include <hip/hip_runtime.h>
#include <stdint.h>

#define NN 20000
#define EE 320000
#define FF 64
#define ROW 128              // B*F
#define KTOP 160000
#define SEGSZ 128
#define NSEG 2500            // EE / SEGSZ
#define NEG_SLOPE 0.2f
#define LN_EPS 1e-5f

// ---------- precompute: rel table [4096] and wa[4][128] ----------
__global__ void precompute_kernel(const float* __restrict__ query,
                                  const float* __restrict__ rel_w,
                                  const float* __restrict__ rel_b,
                                  const float* __restrict__ W,
                                  const float* __restrict__ a,
                                  float* __restrict__ relflat,
                                  float* __restrict__ wa4) {
  int t = blockIdx.x * blockDim.x + threadIdx.x;
  if (t < 4096) {
    int bq = t >> 11, c = t & 2047;
    const float* q = query + bq * FF;
    const float* w = rel_w + (size_t)c * FF;
    float s = rel_b[c];
#pragma unroll
    for (int f = 0; f < FF; f++) s += q[f] * w[f];
    relflat[t] = s;
  }
  if (t < 512) {
    int i = t >> 7, j = t & 127;
    const float* av = a + i * FF;
    const float* w = W + (size_t)j * FF;
    float s = 0.f;
#pragma unroll
    for (int f = 0; f < FF; f++) s += w[f] * av[f];
    wa4[t] = s;
  }
}

__global__ void iterinit_kernel(unsigned int* __restrict__ state, float* __restrict__ racc) {
  int t = threadIdx.x;
  if (t == 0) { state[0] = 0u; state[1] = KTOP; state[2] = 0u; state[3] = 0u; }
  if (t < 128) racc[t] = 0.f;
}

// ---------- edge alpha_raw + segment max ----------
__global__ void edge_alpha_kernel(const int* __restrict__ esrc, const int* __restrict__ rix,
                                  const float* __restrict__ x, const float* __restrict__ relflat,
                                  const float* __restrict__ wa,
                                  float* __restrict__ alpha_raw, unsigned int* __restrict__ segmax) {
  int gid = blockIdx.x * blockDim.x + threadIdx.x;
  int e = gid >> 5;
  int lane = gid & 31;
  if (e >= EE) return;
  int src = esrc[e];
  int r = rix[e];
  int j = lane * 4;
  float4 xv = *(const float4*)(x + (size_t)src * ROW + j);
  float4 rv = *(const float4*)(relflat + r * ROW + j);
  float4 wv = *(const float4*)(wa + j);
  float s = (xv.x + rv.x) * wv.x + (xv.y + rv.y) * wv.y +
            (xv.z + rv.z) * wv.z + (xv.w + rv.w) * wv.w;
#pragma unroll
  for (int off = 16; off > 0; off >>= 1) s += __shfl_xor(s, off, 64);
  if (lane == 0) {
    float v = s > 0.f ? s : NEG_SLOPE * s;
    alpha_raw[e] = v;
    unsigned int b = __float_as_uint(v);
    unsigned int u = (b & 0x80000000u) ? ~b : (b | 0x80000000u);
    atomicMax(segmax + src, u);
  }
}

// ---------- exp(alpha - m[src]) + segment sum ----------
__global__ void ex_kernel(const int* __restrict__ esrc, const float* __restrict__ alpha_raw,
                          const unsigned int* __restrict__ segmax,
                          float* __restrict__ exv, float* __restrict__ denom) {
  int e = blockIdx.x * blockDim.x + threadIdx.x;
  if (e >= EE) return;
  int src = esrc[e];
  unsigned int u = segmax[src];
  float m = (u & 0x80000000u) ? __uint_as_float(u & 0x7FFFFFFFu) : __uint_as_float(~u);
  float v = expf(alpha_raw[e] - m);
  exv[e] = v;
  atomicAdd(denom + src, v);
}

__global__ void alpha_kernel(const int* __restrict__ esrc, const float* __restrict__ exv,
                             const float* __restrict__ denom, float* __restrict__ alpha) {
  int e = blockIdx.x * blockDim.x + threadIdx.x;
  if (e >= EE) return;
  alpha[e] = exv[e] / (denom[esrc[e]] + 1e-16f);
}

// ---------- radix select (4 passes of 8 bits, positive floats -> raw bit order) ----------
__global__ void hist_kernel(const float* __restrict__ alpha, const unsigned int* __restrict__ state,
                            unsigned int* __restrict__ hist, int shift) {
  __shared__ unsigned int h[256];
  for (int i = threadIdx.x; i < 256; i += blockDim.x) h[i] = 0u;
  __syncthreads();
  unsigned int prefix = state[0];
  int stride = gridDim.x * blockDim.x;
  for (int e = blockIdx.x * blockDim.x + threadIdx.x; e < EE; e += stride) {
    unsigned int u = __float_as_uint(alpha[e]);
    if (shift == 24 || (u >> (shift + 8)) == prefix) {
      atomicAdd(&h[(u >> shift) & 255u], 1u);
    }
  }
  __syncthreads();
  for (int i = threadIdx.x; i < 256; i += blockDim.x) {
    unsigned int c = h[i];
    if (c) atomicAdd(hist + i, c);
  }
}

__global__ void select_kernel(unsigned int* __restrict__ state, unsigned int* __restrict__ hist, int shift) {
  __shared__ unsigned int sh[256];
  int t = threadIdx.x;
  if (t < 256) sh[t] = hist[t];
  __syncthreads();
  if (t == 0) {
    unsigned int krem = state[1];
    unsigned int cum = 0;
    int bin = 255;
    for (; bin > 0; bin--) {
      unsigned int c = sh[bin];
      if (cum + c >= krem) break;
      cum += c;
    }
    unsigned int pfx = (shift == 24) ? (unsigned)bin : ((state[0] << 8) | (unsigned)bin);
    state[0] = pfx;
    state[1] = krem - cum;
    if (shift == 0) { state[2] = pfx; state[3] = krem - cum; }
  }
  __syncthreads();
  if (t < 256) hist[t] = 0u;   // ready for next pass / next iteration
}

// ---------- tie handling (lowest-index-first, replicating jax.lax.top_k) ----------
__global__ void tiecnt_kernel(const float* __restrict__ alpha, const unsigned int* __restrict__ state,
                              unsigned int* __restrict__ tiecnt) {
  int s = blockIdx.x * blockDim.x + threadIdx.x;
  if (s >= NSEG) return;
  unsigned int T = state[2];
  unsigned int c = 0;
  const float* p = alpha + (size_t)s * SEGSZ;
  for (int t = 0; t < SEGSZ; t++) c += (__float_as_uint(p[t]) == T) ? 1u : 0u;
  tiecnt[s] = c;
}

__global__ void tiescan_kernel(const unsigned int* __restrict__ tiecnt, unsigned int* __restrict__ tiepref) {
  __shared__ unsigned int sh[1024];
  int t = threadIdx.x;
  int base = t * 3;
  unsigned int c0 = (base     < NSEG) ? tiecnt[base]     : 0u;
  unsigned int c1 = (base + 1 < NSEG) ? tiecnt[base + 1] : 0u;
  unsigned int c2 = (base + 2 < NSEG) ? tiecnt[base + 2] : 0u;
  unsigned int sum = c0 + c1 + c2;
  sh[t] = sum;
  __syncthreads();
  for (int o = 1; o < 1024; o <<= 1) {
    unsigned int v = (t >= o) ? sh[t - o] : 0u;
    __syncthreads();
    sh[t] += v;
    __syncthreads();
  }
  unsigned int excl = sh[t] - sum;
  if (base     < NSEG) tiepref[base]     = excl;
  if (base + 1 < NSEG) tiepref[base + 1] = excl + c0;
  if (base + 2 < NSEG) tiepref[base + 2] = excl + c0 + c1;
}

__global__ void wsel_kernel(const float* __restrict__ alpha, const unsigned int* __restrict__ state,
                            const unsigned int* __restrict__ tiepref, float* __restrict__ wfin) {
  int s = blockIdx.x * blockDim.x + threadIdx.x;
  if (s >= NSEG) return;
  unsigned int T = state[2], need = state[3];
  unsigned int p = tiepref[s];
  for (int t = 0; t < SEGSZ; t++) {
    int e = s * SEGSZ + t;
    float av = alpha[e];
    unsigned int u = __float_as_uint(av);
    float w = 0.f;
    if (u > T) w = av;
    else if (u == T) { if (p < need) w = av; p++; }
    wfin[e] = w;
  }
}

// ---------- weighted scatter-add of msg by dst (upd pre-initialized to x) ----------
__global__ void scatter_kernel(const int* __restrict__ esrc, const int* __restrict__ edst,
                               const int* __restrict__ rix,
                               const float* __restrict__ x, const float* __restrict__ relflat,
                               const float* __restrict__ wfin, float* __restrict__ upd) {
  int gid = blockIdx.x * blockDim.x + threadIdx.x;
  int e = gid >> 5;
  int lane = gid & 31;
  if (e >= EE) return;
  float w = wfin[e];
  if (w == 0.f) return;
  int src = esrc[e], dst = edst[e], r = rix[e];
  int j = lane * 4;
  float4 xv = *(const float4*)(x + (size_t)src * ROW + j);
  float4 rv = *(const float4*)(relflat + r * ROW + j);
  float* o = upd + (size_t)dst * ROW + j;
  atomicAdd(o + 0, w * (xv.x + rv.x));
  atomicAdd(o + 1, w * (xv.y + rv.y));
  atomicAdd(o + 2, w * (xv.z + rv.z));
  atomicAdd(o + 3, w * (xv.w + rv.w));
}

// ---------- readout mean + trans_readout linear ----------
__global__ void readout_kernel(const float* __restrict__ x, float* __restrict__ racc) {
  int j = threadIdx.x;  // 0..127
  float acc = 0.f;
  for (int n = blockIdx.x; n < NN; n += gridDim.x) acc += x[(size_t)n * ROW + j];
  atomicAdd(racc + j, acc);
}

__global__ void trt_kernel(const float* __restrict__ racc, const float* __restrict__ tr_w,
                           const float* __restrict__ tr_b, float* __restrict__ trt) {
  int t = threadIdx.x;  // 0..127
  int b = t >> 6, f = t & 63;
  const float invN = 1.0f / (float)NN;
  float s = tr_b[f];
#pragma unroll
  for (int g = 0; g < FF; g++) s += (racc[b * FF + g] * invN) * tr_w[f * FF + g];
  trt[t] = s;
}

// ---------- per-node linear + LN + ELU + residual (in-place on x) ----------
__global__ __launch_bounds__(256) void node_kernel(const float* __restrict__ upd,
                                                   const float* __restrict__ layer_w,
                                                   const float* __restrict__ layer_b,
                                                   const float* __restrict__ trt,
                                                   const float* __restrict__ ln_g,
                                                   const float* __restrict__ ln_b,
                                                   float* __restrict__ x) {
  __shared__ float lwT[ROW * FF];  // lwT[c*64+f] = layer_w[f*128+c], 32 KB
  for (int idx = threadIdx.x; idx < ROW * FF; idx += blockDim.x) {
    int c = idx >> 6, f = idx & 63;
    lwT[idx] = layer_w[f * ROW + c];
  }
  __syncthreads();
  int wave = threadIdx.x >> 6;
  int lane = threadIdx.x & 63;
  float lb = layer_b[lane];
  float t0 = trt[lane] + lb;
  float t1 = trt[64 + lane] + lb;
  float g_ = ln_g[lane], bta = ln_b[lane];
  for (int n = blockIdx.x * 4 + wave; n < NN; n += gridDim.x * 4) {
    const float* xr = x + (size_t)n * ROW;
    const float* ur = upd + (size_t)n * ROW;
    float x0 = xr[lane], x1 = xr[64 + lane];
    float u0 = ur[lane], u1 = ur[64 + lane];
    float acc0 = t0, acc1 = t1;
#pragma unroll 16
    for (int gg = 0; gg < FF; gg++) {
      float aw = lwT[gg * FF + lane];
      float bw = lwT[(FF + gg) * FF + lane];
      float xb0 = __shfl(x0, gg, 64);
      float xb1 = __shfl(x1, gg, 64);
      float ub0 = __shfl(u0, gg, 64);
      float ub1 = __shfl(u1, gg, 64);
      acc0 += xb0 * aw + ub0 * bw;
      acc1 += xb1 * aw + ub1 * bw;
    }
    float s0 = acc0, q0 = acc0 * acc0, s1 = acc1, q1 = acc1 * acc1;
#pragma unroll
    for (int off = 32; off > 0; off >>= 1) {
      s0 += __shfl_xor(s0, off, 64);
      q0 += __shfl_xor(q0, off, 64);
      s1 += __shfl_xor(s1, off, 64);
      q1 += __shfl_xor(q1, off, 64);
    }
    const float invF = 1.0f / (float)FF;
    float mu0 = s0 * invF, mu1 = s1 * invF;
    float var0 = q0 * invF - mu0 * mu0;
    float var1 = q1 * invF - mu1 * mu1;
    float r0 = 1.0f / sqrtf(var0 + LN_EPS);
    float r1 = 1.0f / sqrtf(var1 + LN_EPS);
    float o0 = (acc0 - mu0) * r0 * g_ + bta;
    float o1 = (acc1 - mu1) * r1 * g_ + bta;
    float h0 = o0 > 0.f ? o0 : expm1f(o0);
    float h1 = o1 > 0.f ? o1 : expm1f(o1);
    x[(size_t)n * ROW + lane] = h0 + x0;
    x[(size_t)n * ROW + 64 + lane] = h1 + x1;
  }
}

extern "C" void kernel_launch(void* const* d_in, const int* in_sizes, int n_in,
                              void* d_out, int out_size, void* d_ws, size_t ws_size,
                              hipStream_t stream) {
  const int* ei = (const int*)d_in[0];
  const int* esrc = ei;
  const int* edst = ei + EE;
  const int* rix = (const int*)d_in[1];
  const float* boundary = (const float*)d_in[2];
  const float* query = (const float*)d_in[3];
  const float* rel_w = (const float*)d_in[4];
  const float* rel_b = (const float*)d_in[5];
  const float* layer_w = (const float*)d_in[6];
  const float* layer_b = (const float*)d_in[7];
  const float* tr_w = (const float*)d_in[8];
  const float* tr_b = (const float*)d_in[9];
  const float* Wm = (const float*)d_in[10];
  const float* av = (const float*)d_in[11];
  const float* ln_g = (const float*)d_in[12];
  const float* ln_b = (const float*)d_in[13];
  float* x = (float*)d_out;

  char* ws = (char*)d_ws;
  size_t off = 0;
  auto allocf = [&](size_t n) -> float* {
    float* p = (float*)(ws + off);
    off += ((n * 4 + 255) / 256) * 256;
    return p;
  };
  auto allocu = [&](size_t n) -> unsigned int* {
    unsigned int* p = (unsigned int*)(ws + off);
    off += ((n * 4 + 255) / 256) * 256;
    return p;
  };
  float* relflat = allocf(4096);
  float* wa4 = allocf(512);
  float* bufA = allocf(EE);        // alpha_raw, then alpha
  float* bufB = allocf(EE);        // exv, then wfin
  float* denom = allocf(NN);
  float* upd = allocf((size_t)NN * ROW);
  float* racc = allocf(128);
  float* trt = allocf(128);
  unsigned int* segmax = allocu(NN);
  unsigned int* hist = allocu(256);
  unsigned int* state = allocu(8);
  unsigned int* tiecnt = allocu(NSEG);
  unsigned int* tiepref = allocu(NSEG);

  hipMemcpyAsync(x, boundary, (size_t)NN * ROW * 4, hipMemcpyDeviceToDevice, stream);
  hipMemsetAsync(hist, 0, 256 * 4, stream);
  precompute_kernel<<<16, 256, 0, stream>>>(query, rel_w, rel_b, Wm, av, relflat, wa4);

  for (int it = 0; it < 4; it++) {
    hipMemsetAsync(segmax, 0, NN * 4, stream);
    hipMemsetAsync(denom, 0, NN * 4, stream);
    iterinit_kernel<<<1, 128, 0, stream>>>(state, racc);

    edge_alpha_kernel<<<(EE * 32) / 256, 256, 0, stream>>>(esrc, rix, x, relflat,
                                                           wa4 + it * 128, bufA, segmax);
    ex_kernel<<<EE / 256, 256, 0, stream>>>(esrc, bufA, segmax, bufB, denom);
    alpha_kernel<<<EE / 256, 256, 0, stream>>>(esrc, bufB, denom, bufA);  // bufA = alpha

    for (int shift = 24; shift >= 0; shift -= 8) {
      hist_kernel<<<320, 256, 0, stream>>>(bufA, state, hist, shift);
      select_kernel<<<1, 256, 0, stream>>>(state, hist, shift);
    }
    tiecnt_kernel<<<(NSEG + 255) / 256, 256, 0, stream>>>(bufA, state, tiecnt);
    tiescan_kernel<<<1, 1024, 0, stream>>>(tiecnt, tiepref);
    wsel_kernel<<<(NSEG + 255) / 256, 256, 0, stream>>>(bufA, state, tiepref, bufB);  // bufB = w

    hipMemcpyAsync(upd, x, (size_t)NN * ROW * 4, hipMemcpyDeviceToDevice, stream);
    scatter_kernel<<<(EE * 32) / 256, 256, 0, stream>>>(esrc, edst, rix, x, relflat, bufB, upd);

    readout_kernel<<<256, 128, 0, stream>>>(x, racc);
    trt_kernel<<<1, 128, 0, stream>>>(racc, tr_w, tr_b, trt);
    node_kernel<<<1250, 256, 0, stream>>>(upd, layer_w, layer_b, trt, ln_g, ln_b, x);
  }
}

// Round 2
// 1641.625 us; speedup vs baseline: 1.4656x; 1.4656x over previous
//
#include <hip/hip_runtime.h>
#include <stdint.h>

#define NN 20000
#define EE 320000
#define FF 64
#define ROW 128              // B*F
#define KTOP 160000
#define SEGSZ 128
#define NSEG 2500            // EE / SEGSZ
#define NEG_SLOPE 0.2f
#define LN_EPS 1e-5f

// ---------- precompute: rel table [4096] and wa[4][128] ----------
__global__ void precompute_kernel(const float* __restrict__ query,
                                  const float* __restrict__ rel_w,
                                  const float* __restrict__ rel_b,
                                  const float* __restrict__ W,
                                  const float* __restrict__ a,
                                  float* __restrict__ relflat,
                                  float* __restrict__ wa4) {
  int t = blockIdx.x * blockDim.x + threadIdx.x;
  if (t < 4096) {
    int bq = t >> 11, c = t & 2047;
    const float* q = query + bq * FF;
    const float* w = rel_w + (size_t)c * FF;
    float s = rel_b[c];
#pragma unroll
    for (int f = 0; f < FF; f++) s += q[f] * w[f];
    relflat[t] = s;
  }
  if (t < 512) {
    int i = t >> 7, j = t & 127;
    const float* av = a + i * FF;
    const float* w = W + (size_t)j * FF;
    float s = 0.f;
#pragma unroll
    for (int f = 0; f < FF; f++) s += w[f] * av[f];
    wa4[t] = s;
  }
}

__global__ void iterinit_kernel(unsigned int* __restrict__ state, float* __restrict__ racc) {
  int t = threadIdx.x;
  if (t == 0) { state[0] = 0u; state[1] = KTOP; state[2] = 0u; state[3] = 0u; }
  if (t < 128) racc[t] = 0.f;
}

// ---------- CSR-by-dst build (once per launch; edge_index is launch-constant) ----------
__global__ void degcnt_kernel(const int* __restrict__ edst, unsigned int* __restrict__ deg) {
  int e = blockIdx.x * blockDim.x + threadIdx.x;
  if (e < EE) atomicAdd(deg + edst[e], 1u);
}

__global__ void scan_kernel(const unsigned int* __restrict__ deg,
                            unsigned int* __restrict__ rowptr,
                            unsigned int* __restrict__ rowfill) {
  __shared__ unsigned int sh[1024];
  int t = threadIdx.x;
  const int PER = 20;  // 1024*20 >= NN
  unsigned int loc[PER];
  unsigned int sum = 0;
  int base = t * PER;
#pragma unroll
  for (int i = 0; i < PER; i++) {
    int n = base + i;
    unsigned int d = (n < NN) ? deg[n] : 0u;
    loc[i] = sum;
    sum += d;
  }
  sh[t] = sum;
  __syncthreads();
  for (int o = 1; o < 1024; o <<= 1) {
    unsigned int v = (t >= o) ? sh[t - o] : 0u;
    __syncthreads();
    sh[t] += v;
    __syncthreads();
  }
  unsigned int excl = sh[t] - sum;
#pragma unroll
  for (int i = 0; i < PER; i++) {
    int n = base + i;
    if (n < NN) {
      unsigned int rp = excl + loc[i];
      rowptr[n] = rp;
      rowfill[n] = rp;
    }
  }
  if (t == 1023) rowptr[NN] = EE;
}

__global__ void fill_kernel(const int* __restrict__ edst, unsigned int* __restrict__ rowfill,
                            int* __restrict__ csre) {
  int e = blockIdx.x * blockDim.x + threadIdx.x;
  if (e < EE) {
    unsigned int slot = atomicAdd(rowfill + edst[e], 1u);
    csre[slot] = e;
  }
}

// ---------- edge alpha_raw + segment max ----------
__global__ void edge_alpha_kernel(const int* __restrict__ esrc, const int* __restrict__ rix,
                                  const float* __restrict__ x, const float* __restrict__ relflat,
                                  const float* __restrict__ wa,
                                  float* __restrict__ alpha_raw, unsigned int* __restrict__ segmax) {
  int gid = blockIdx.x * blockDim.x + threadIdx.x;
  int e = gid >> 5;
  int lane = gid & 31;
  if (e >= EE) return;
  int src = esrc[e];
  int r = rix[e];
  int j = lane * 4;
  float4 xv = *(const float4*)(x + (size_t)src * ROW + j);
  float4 rv = *(const float4*)(relflat + r * ROW + j);
  float4 wv = *(const float4*)(wa + j);
  float s = (xv.x + rv.x) * wv.x + (xv.y + rv.y) * wv.y +
            (xv.z + rv.z) * wv.z + (xv.w + rv.w) * wv.w;
#pragma unroll
  for (int off = 16; off > 0; off >>= 1) s += __shfl_xor(s, off, 64);
  if (lane == 0) {
    float v = s > 0.f ? s : NEG_SLOPE * s;
    alpha_raw[e] = v;
    unsigned int b = __float_as_uint(v);
    unsigned int u = (b & 0x80000000u) ? ~b : (b | 0x80000000u);
    atomicMax(segmax + src, u);
  }
}

// ---------- exp(alpha - m[src]) + segment sum ----------
__global__ void ex_kernel(const int* __restrict__ esrc, const float* __restrict__ alpha_raw,
                          const unsigned int* __restrict__ segmax,
                          float* __restrict__ exv, float* __restrict__ denom) {
  int e = blockIdx.x * blockDim.x + threadIdx.x;
  if (e >= EE) return;
  int src = esrc[e];
  unsigned int u = segmax[src];
  float m = (u & 0x80000000u) ? __uint_as_float(u & 0x7FFFFFFFu) : __uint_as_float(~u);
  float v = expf(alpha_raw[e] - m);
  exv[e] = v;
  atomicAdd(denom + src, v);
}

// ---------- radix select pass 1 fused with alpha normalize ----------
__global__ void hist0_kernel(const int* __restrict__ esrc, const float* __restrict__ exv,
                             const float* __restrict__ denom, float* __restrict__ alpha,
                             unsigned int* __restrict__ hist) {
  __shared__ unsigned int h[256];
  for (int i = threadIdx.x; i < 256; i += blockDim.x) h[i] = 0u;
  __syncthreads();
  int stride = gridDim.x * blockDim.x;
  for (int e = blockIdx.x * blockDim.x + threadIdx.x; e < EE; e += stride) {
    float av = exv[e] / (denom[esrc[e]] + 1e-16f);
    alpha[e] = av;
    unsigned int u = __float_as_uint(av);
    atomicAdd(&h[(u >> 24) & 255u], 1u);
  }
  __syncthreads();
  for (int i = threadIdx.x; i < 256; i += blockDim.x) {
    unsigned int c = h[i];
    if (c) atomicAdd(hist + i, c);
  }
}

__global__ void hist_kernel(const float* __restrict__ alpha, const unsigned int* __restrict__ state,
                            unsigned int* __restrict__ hist, int shift) {
  __shared__ unsigned int h[256];
  for (int i = threadIdx.x; i < 256; i += blockDim.x) h[i] = 0u;
  __syncthreads();
  unsigned int prefix = state[0];
  int stride = gridDim.x * blockDim.x;
  for (int e = blockIdx.x * blockDim.x + threadIdx.x; e < EE; e += stride) {
    unsigned int u = __float_as_uint(alpha[e]);
    if ((u >> (shift + 8)) == prefix) {
      atomicAdd(&h[(u >> shift) & 255u], 1u);
    }
  }
  __syncthreads();
  for (int i = threadIdx.x; i < 256; i += blockDim.x) {
    unsigned int c = h[i];
    if (c) atomicAdd(hist + i, c);
  }
}

__global__ void select_kernel(unsigned int* __restrict__ state, unsigned int* __restrict__ hist, int shift) {
  __shared__ unsigned int sh[256];
  int t = threadIdx.x;
  if (t < 256) sh[t] = hist[t];
  __syncthreads();
  if (t == 0) {
    unsigned int krem = state[1];
    unsigned int cum = 0;
    int bin = 255;
    for (; bin > 0; bin--) {
      unsigned int c = sh[bin];
      if (cum + c >= krem) break;
      cum += c;
    }
    unsigned int pfx = (shift == 24) ? (unsigned)bin : ((state[0] << 8) | (unsigned)bin);
    state[0] = pfx;
    state[1] = krem - cum;
    if (shift == 0) { state[2] = pfx; state[3] = krem - cum; }
  }
  __syncthreads();
  if (t < 256) hist[t] = 0u;   // ready for next pass / next iteration
}

// ---------- tie handling (lowest-index-first, replicating jax.lax.top_k) ----------
__global__ void tiecnt_kernel(const float* __restrict__ alpha, const unsigned int* __restrict__ state,
                              unsigned int* __restrict__ tiecnt) {
  int s = blockIdx.x * blockDim.x + threadIdx.x;
  if (s >= NSEG) return;
  unsigned int T = state[2];
  unsigned int c = 0;
  const float* p = alpha + (size_t)s * SEGSZ;
  for (int t = 0; t < SEGSZ; t++) c += (__float_as_uint(p[t]) == T) ? 1u : 0u;
  tiecnt[s] = c;
}

__global__ void tiescan_kernel(const unsigned int* __restrict__ tiecnt, unsigned int* __restrict__ tiepref) {
  __shared__ unsigned int sh[1024];
  int t = threadIdx.x;
  int base = t * 3;
  unsigned int c0 = (base     < NSEG) ? tiecnt[base]     : 0u;
  unsigned int c1 = (base + 1 < NSEG) ? tiecnt[base + 1] : 0u;
  unsigned int c2 = (base + 2 < NSEG) ? tiecnt[base + 2] : 0u;
  unsigned int sum = c0 + c1 + c2;
  sh[t] = sum;
  __syncthreads();
  for (int o = 1; o < 1024; o <<= 1) {
    unsigned int v = (t >= o) ? sh[t - o] : 0u;
    __syncthreads();
    sh[t] += v;
    __syncthreads();
  }
  unsigned int excl = sh[t] - sum;
  if (base     < NSEG) tiepref[base]     = excl;
  if (base + 1 < NSEG) tiepref[base + 1] = excl + c0;
  if (base + 2 < NSEG) tiepref[base + 2] = excl + c0 + c1;
}

__global__ void wsel_kernel(const float* __restrict__ alpha, const unsigned int* __restrict__ state,
                            const unsigned int* __restrict__ tiepref, float* __restrict__ wfin) {
  int s = blockIdx.x * blockDim.x + threadIdx.x;
  if (s >= NSEG) return;
  unsigned int T = state[2], need = state[3];
  unsigned int p = tiepref[s];
  for (int t = 0; t < SEGSZ; t++) {
    int e = s * SEGSZ + t;
    float av = alpha[e];
    unsigned int u = __float_as_uint(av);
    float w = 0.f;
    if (u > T) w = av;
    else if (u == T) { if (p < need) w = av; p++; }
    wfin[e] = w;
  }
}

// ---------- gather-reduce update by dst (CSR), upd = sum(w*msg) + x ----------
__global__ __launch_bounds__(256) void update_kernel(const int* __restrict__ esrc,
                                                     const int* __restrict__ rix,
                                                     const unsigned int* __restrict__ rowptr,
                                                     const int* __restrict__ csre,
                                                     const float* __restrict__ x,
                                                     const float* __restrict__ relflat,
                                                     const float* __restrict__ wfin,
                                                     float* __restrict__ upd) {
  int wave = threadIdx.x >> 6;
  int lane = threadIdx.x & 63;
  for (int n = blockIdx.x * 4 + wave; n < NN; n += gridDim.x * 4) {
    unsigned int p0 = rowptr[n], p1 = rowptr[n + 1];
    float acc0 = x[(size_t)n * ROW + lane];
    float acc1 = x[(size_t)n * ROW + 64 + lane];
    for (unsigned int p = p0; p < p1; p++) {
      int e = csre[p];
      float w = wfin[e];
      if (w == 0.f) continue;
      int src = esrc[e], r = rix[e];
      const float* xr = x + (size_t)src * ROW;
      const float* rr = relflat + r * ROW;
      acc0 += w * (xr[lane] + rr[lane]);
      acc1 += w * (xr[64 + lane] + rr[64 + lane]);
    }
    upd[(size_t)n * ROW + lane] = acc0;
    upd[(size_t)n * ROW + 64 + lane] = acc1;
  }
}

// ---------- readout mean + trans_readout linear ----------
__global__ void readout_kernel(const float* __restrict__ x, float* __restrict__ racc) {
  int j = threadIdx.x;  // 0..127
  float acc = 0.f;
  for (int n = blockIdx.x; n < NN; n += gridDim.x) acc += x[(size_t)n * ROW + j];
  atomicAdd(racc + j, acc);
}

__global__ void trt_kernel(const float* __restrict__ racc, const float* __restrict__ tr_w,
                           const float* __restrict__ tr_b, float* __restrict__ trt) {
  int t = threadIdx.x;  // 0..127
  int b = t >> 6, f = t & 63;
  const float invN = 1.0f / (float)NN;
  float s = tr_b[f];
#pragma unroll
  for (int g = 0; g < FF; g++) s += (racc[b * FF + g] * invN) * tr_w[f * FF + g];
  trt[t] = s;
}

// ---------- per-node linear + LN + ELU + residual (in-place on x) ----------
__global__ __launch_bounds__(256) void node_kernel(const float* __restrict__ upd,
                                                   const float* __restrict__ layer_w,
                                                   const float* __restrict__ layer_b,
                                                   const float* __restrict__ trt,
                                                   const float* __restrict__ ln_g,
                                                   const float* __restrict__ ln_b,
                                                   float* __restrict__ x) {
  __shared__ float lwT[ROW * FF];  // lwT[c*64+f] = layer_w[f*128+c], 32 KB
  for (int idx = threadIdx.x; idx < ROW * FF; idx += blockDim.x) {
    int c = idx >> 6, f = idx & 63;
    lwT[idx] = layer_w[f * ROW + c];
  }
  __syncthreads();
  int wave = threadIdx.x >> 6;
  int lane = threadIdx.x & 63;
  float lb = layer_b[lane];
  float t0 = trt[lane] + lb;
  float t1 = trt[64 + lane] + lb;
  float g_ = ln_g[lane], bta = ln_b[lane];
  for (int n = blockIdx.x * 4 + wave; n < NN; n += gridDim.x * 4) {
    const float* xr = x + (size_t)n * ROW;
    const float* ur = upd + (size_t)n * ROW;
    float x0 = xr[lane], x1 = xr[64 + lane];
    float u0 = ur[lane], u1 = ur[64 + lane];
    float acc0 = t0, acc1 = t1;
#pragma unroll 16
    for (int gg = 0; gg < FF; gg++) {
      float aw = lwT[gg * FF + lane];
      float bw = lwT[(FF + gg) * FF + lane];
      float xb0 = __shfl(x0, gg, 64);
      float xb1 = __shfl(x1, gg, 64);
      float ub0 = __shfl(u0, gg, 64);
      float ub1 = __shfl(u1, gg, 64);
      acc0 += xb0 * aw + ub0 * bw;
      acc1 += xb1 * aw + ub1 * bw;
    }
    float s0 = acc0, q0 = acc0 * acc0, s1 = acc1, q1 = acc1 * acc1;
#pragma unroll
    for (int off = 32; off > 0; off >>= 1) {
      s0 += __shfl_xor(s0, off, 64);
      q0 += __shfl_xor(q0, off, 64);
      s1 += __shfl_xor(s1, off, 64);
      q1 += __shfl_xor(q1, off, 64);
    }
    const float invF = 1.0f / (float)FF;
    float mu0 = s0 * invF, mu1 = s1 * invF;
    float var0 = q0 * invF - mu0 * mu0;
    float var1 = q1 * invF - mu1 * mu1;
    float r0 = 1.0f / sqrtf(var0 + LN_EPS);
    float r1 = 1.0f / sqrtf(var1 + LN_EPS);
    float o0 = (acc0 - mu0) * r0 * g_ + bta;
    float o1 = (acc1 - mu1) * r1 * g_ + bta;
    float h0 = o0 > 0.f ? o0 : expm1f(o0);
    float h1 = o1 > 0.f ? o1 : expm1f(o1);
    x[(size_t)n * ROW + lane] = h0 + x0;
    x[(size_t)n * ROW + 64 + lane] = h1 + x1;
  }
}

extern "C" void kernel_launch(void* const* d_in, const int* in_sizes, int n_in,
                              void* d_out, int out_size, void* d_ws, size_t ws_size,
                              hipStream_t stream) {
  const int* ei = (const int*)d_in[0];
  const int* esrc = ei;
  const int* edst = ei + EE;
  const int* rix = (const int*)d_in[1];
  const float* boundary = (const float*)d_in[2];
  const float* query = (const float*)d_in[3];
  const float* rel_w = (const float*)d_in[4];
  const float* rel_b = (const float*)d_in[5];
  const float* layer_w = (const float*)d_in[6];
  const float* layer_b = (const float*)d_in[7];
  const float* tr_w = (const float*)d_in[8];
  const float* tr_b = (const float*)d_in[9];
  const float* Wm = (const float*)d_in[10];
  const float* av = (const float*)d_in[11];
  const float* ln_g = (const float*)d_in[12];
  const float* ln_b = (const float*)d_in[13];
  float* x = (float*)d_out;

  char* ws = (char*)d_ws;
  size_t off = 0;
  auto allocf = [&](size_t n) -> float* {
    float* p = (float*)(ws + off);
    off += ((n * 4 + 255) / 256) * 256;
    return p;
  };
  auto allocu = [&](size_t n) -> unsigned int* {
    unsigned int* p = (unsigned int*)(ws + off);
    off += ((n * 4 + 255) / 256) * 256;
    return p;
  };
  float* relflat = allocf(4096);
  float* wa4 = allocf(512);
  float* bufA = allocf(EE);        // alpha_raw, then alpha
  float* bufB = allocf(EE);        // exv, then wfin
  float* denom = allocf(NN);
  float* upd = allocf((size_t)NN * ROW);
  float* racc = allocf(128);
  float* trt = allocf(128);
  unsigned int* segmax = allocu(NN);
  unsigned int* hist = allocu(256);
  unsigned int* state = allocu(8);
  unsigned int* tiecnt = allocu(NSEG);
  unsigned int* tiepref = allocu(NSEG);
  unsigned int* deg = allocu(NN);
  unsigned int* rowptr = allocu(NN + 1);
  unsigned int* rowfill = allocu(NN);
  int* csre = (int*)allocu(EE);

  hipMemcpyAsync(x, boundary, (size_t)NN * ROW * 4, hipMemcpyDeviceToDevice, stream);
  hipMemsetAsync(hist, 0, 256 * 4, stream);
  hipMemsetAsync(deg, 0, NN * 4, stream);
  precompute_kernel<<<16, 256, 0, stream>>>(query, rel_w, rel_b, Wm, av, relflat, wa4);

  // CSR by dst (edge_index is constant for this launch)
  degcnt_kernel<<<EE / 256, 256, 0, stream>>>(edst, deg);
  scan_kernel<<<1, 1024, 0, stream>>>(deg, rowptr, rowfill);
  fill_kernel<<<EE / 256, 256, 0, stream>>>(edst, rowfill, csre);

  for (int it = 0; it < 4; it++) {
    hipMemsetAsync(segmax, 0, NN * 4, stream);
    hipMemsetAsync(denom, 0, NN * 4, stream);
    iterinit_kernel<<<1, 128, 0, stream>>>(state, racc);

    edge_alpha_kernel<<<(EE * 32) / 256, 256, 0, stream>>>(esrc, rix, x, relflat,
                                                           wa4 + it * 128, bufA, segmax);
    ex_kernel<<<EE / 256, 256, 0, stream>>>(esrc, bufA, segmax, bufB, denom);

    hist0_kernel<<<320, 256, 0, stream>>>(esrc, bufB, denom, bufA, hist);  // bufA = alpha
    select_kernel<<<1, 256, 0, stream>>>(state, hist, 24);
    for (int shift = 16; shift >= 0; shift -= 8) {
      hist_kernel<<<320, 256, 0, stream>>>(bufA, state, hist, shift);
      select_kernel<<<1, 256, 0, stream>>>(state, hist, shift);
    }
    tiecnt_kernel<<<(NSEG + 255) / 256, 256, 0, stream>>>(bufA, state, tiecnt);
    tiescan_kernel<<<1, 1024, 0, stream>>>(tiecnt, tiepref);
    wsel_kernel<<<(NSEG + 255) / 256, 256, 0, stream>>>(bufA, state, tiepref, bufB);  // bufB = w

    update_kernel<<<1250, 256, 0, stream>>>(esrc, rix, rowptr, csre, x, relflat, bufB, upd);

    readout_kernel<<<256, 128, 0, stream>>>(x, racc);
    trt_kernel<<<1, 128, 0, stream>>>(racc, tr_w, tr_b, trt);
    node_kernel<<<1250, 256, 0, stream>>>(upd, layer_w, layer_b, trt, ln_g, ln_b, x);
  }
}

// Round 3
// 1334.862 us; speedup vs baseline: 1.8024x; 1.2298x over previous
//
#include <hip/hip_runtime.h>
#include <stdint.h>

#define NN 20000
#define EE 320000
#define FF 64
#define ROW 128              // B*F
#define KTOP 160000
#define NEG_SLOPE 0.2f
#define LN_EPS 1e-5f

// ---------- precompute: rel table [4096] and wa[4][128] ----------
__global__ void precompute_kernel(const float* __restrict__ query,
                                  const float* __restrict__ rel_w,
                                  const float* __restrict__ rel_b,
                                  const float* __restrict__ W,
                                  const float* __restrict__ a,
                                  float* __restrict__ relflat,
                                  float* __restrict__ wa4) {
  int t = blockIdx.x * blockDim.x + threadIdx.x;
  if (t < 4096) {
    int bq = t >> 11, c = t & 2047;
    const float* q = query + bq * FF;
    const float* w = rel_w + (size_t)c * FF;
    float s = rel_b[c];
#pragma unroll
    for (int f = 0; f < FF; f++) s += q[f] * w[f];
    relflat[t] = s;
  }
  if (t < 512) {
    int i = t >> 7, j = t & 127;
    const float* av = a + i * FF;
    const float* w = W + (size_t)j * FF;
    float s = 0.f;
#pragma unroll
    for (int f = 0; f < FF; f++) s += w[f] * av[f];
    wa4[t] = s;
  }
}

// state[0]=prefix state[1]=krem state[2]=T state[3]=need state[4]=tiecount
__global__ void iterinit_kernel(unsigned int* __restrict__ state,
                                const float* __restrict__ relflat,
                                const float* __restrict__ wa,
                                float* __restrict__ relwa) {
  int t = threadIdx.x;
  if (t == 0) { state[0] = 0u; state[1] = KTOP; state[2] = 0u; state[3] = 0u; state[4] = 0u; }
  if (t < 32) {
    float s = 0.f;
#pragma unroll 16
    for (int j = 0; j < ROW; j++) s += relflat[t * ROW + j] * wa[j];
    relwa[t] = s;
  }
}

// ---------- CSR-by-dst build (once per launch; edge_index is launch-constant) ----------
__global__ void degcnt_kernel(const int* __restrict__ edst, unsigned int* __restrict__ deg) {
  int e = blockIdx.x * blockDim.x + threadIdx.x;
  if (e < EE) atomicAdd(deg + edst[e], 1u);
}

__global__ void scan_kernel(const unsigned int* __restrict__ deg,
                            unsigned int* __restrict__ rowptr,
                            unsigned int* __restrict__ rowfill) {
  __shared__ unsigned int sh[1024];
  int t = threadIdx.x;
  const int PER = 20;  // 1024*20 >= NN
  unsigned int loc[PER];
  unsigned int sum = 0;
  int base = t * PER;
#pragma unroll
  for (int i = 0; i < PER; i++) {
    int n = base + i;
    unsigned int d = (n < NN) ? deg[n] : 0u;
    loc[i] = sum;
    sum += d;
  }
  sh[t] = sum;
  __syncthreads();
  for (int o = 1; o < 1024; o <<= 1) {
    unsigned int v = (t >= o) ? sh[t - o] : 0u;
    __syncthreads();
    sh[t] += v;
    __syncthreads();
  }
  unsigned int excl = sh[t] - sum;
#pragma unroll
  for (int i = 0; i < PER; i++) {
    int n = base + i;
    if (n < NN) {
      unsigned int rp = excl + loc[i];
      rowptr[n] = rp;
      rowfill[n] = rp;
    }
  }
  if (t == 1023) rowptr[NN] = EE;
}

__global__ void fill_kernel(const int* __restrict__ edst, unsigned int* __restrict__ rowfill,
                            int* __restrict__ csre) {
  int e = blockIdx.x * blockDim.x + threadIdx.x;
  if (e < EE) {
    unsigned int slot = atomicAdd(rowfill + edst[e], 1u);
    csre[slot] = e;
  }
}

// ---------- nodewa init (iter 0): nodewa[n] = x[n].flat . wa ----------
__global__ void nodewa_kernel(const float* __restrict__ x, const float* __restrict__ wa,
                              float* __restrict__ nodewa) {
  int wave = threadIdx.x >> 6, lane = threadIdx.x & 63;
  float w0 = wa[lane], w1 = wa[64 + lane];
  for (int n = blockIdx.x * 4 + wave; n < NN; n += gridDim.x * 4) {
    float s = x[(size_t)n * ROW + lane] * w0 + x[(size_t)n * ROW + 64 + lane] * w1;
#pragma unroll
    for (int off = 32; off > 0; off >>= 1) s += __shfl_xor(s, off, 64);
    if (lane == 0) nodewa[n] = s;
  }
}

// ---------- per-edge alpha_raw (separable) + segment max ----------
__global__ void segmax_kernel(const int* __restrict__ esrc, const int* __restrict__ rix,
                              const float* __restrict__ nodewa, const float* __restrict__ relwa,
                              unsigned int* __restrict__ segmax) {
  int e = blockIdx.x * blockDim.x + threadIdx.x;
  if (e >= EE) return;
  int src = esrc[e];
  float s = nodewa[src] + relwa[rix[e]];
  float v = s > 0.f ? s : NEG_SLOPE * s;
  unsigned int b = __float_as_uint(v);
  unsigned int u = (b & 0x80000000u) ? ~b : (b | 0x80000000u);
  atomicMax(segmax + src, u);
}

// ---------- exp(alpha - m[src]) + segment sum ----------
__global__ void ex_kernel(const int* __restrict__ esrc, const int* __restrict__ rix,
                          const float* __restrict__ nodewa, const float* __restrict__ relwa,
                          const unsigned int* __restrict__ segmax,
                          float* __restrict__ exv, float* __restrict__ denom) {
  int e = blockIdx.x * blockDim.x + threadIdx.x;
  if (e >= EE) return;
  int src = esrc[e];
  float s = nodewa[src] + relwa[rix[e]];
  float v = s > 0.f ? s : NEG_SLOPE * s;
  unsigned int u = segmax[src];
  float m = (u & 0x80000000u) ? __uint_as_float(u & 0x7FFFFFFFu) : __uint_as_float(~u);
  float ev = expf(v - m);
  exv[e] = ev;
  atomicAdd(denom + src, ev);
}

// ---------- radix select pass 1 fused with alpha normalize ----------
__global__ void hist0_kernel(const int* __restrict__ esrc, const float* __restrict__ exv,
                             const float* __restrict__ denom, float* __restrict__ alpha,
                             unsigned int* __restrict__ hist) {
  __shared__ unsigned int h[256];
  for (int i = threadIdx.x; i < 256; i += blockDim.x) h[i] = 0u;
  __syncthreads();
  int stride = gridDim.x * blockDim.x;
  for (int e = blockIdx.x * blockDim.x + threadIdx.x; e < EE; e += stride) {
    float av = exv[e] / (denom[esrc[e]] + 1e-16f);
    alpha[e] = av;
    unsigned int u = __float_as_uint(av);
    atomicAdd(&h[(u >> 24) & 255u], 1u);
  }
  __syncthreads();
  for (int i = threadIdx.x; i < 256; i += blockDim.x) {
    unsigned int c = h[i];
    if (c) atomicAdd(hist + i, c);
  }
}

__global__ void hist_kernel(const float* __restrict__ alpha, const unsigned int* __restrict__ state,
                            unsigned int* __restrict__ hist, int shift) {
  __shared__ unsigned int h[256];
  for (int i = threadIdx.x; i < 256; i += blockDim.x) h[i] = 0u;
  __syncthreads();
  unsigned int prefix = state[0];
  int stride = gridDim.x * blockDim.x;
  for (int e = blockIdx.x * blockDim.x + threadIdx.x; e < EE; e += stride) {
    unsigned int u = __float_as_uint(alpha[e]);
    if ((u >> (shift + 8)) == prefix) {
      atomicAdd(&h[(u >> shift) & 255u], 1u);
    }
  }
  __syncthreads();
  for (int i = threadIdx.x; i < 256; i += blockDim.x) {
    unsigned int c = h[i];
    if (c) atomicAdd(hist + i, c);
  }
}

__global__ void select_kernel(unsigned int* __restrict__ state, unsigned int* __restrict__ hist, int shift) {
  __shared__ unsigned int sh[256];
  int t = threadIdx.x;
  if (t < 256) sh[t] = hist[t];
  __syncthreads();
  if (t == 0) {
    unsigned int krem = state[1];
    unsigned int cum = 0;
    int bin = 255;
    for (; bin > 0; bin--) {
      unsigned int c = sh[bin];
      if (cum + c >= krem) break;
      cum += c;
    }
    unsigned int pfx = (shift == 24) ? (unsigned)bin : ((state[0] << 8) | (unsigned)bin);
    state[0] = pfx;
    state[1] = krem - cum;
    if (shift == 0) { state[2] = pfx; state[3] = krem - cum; }
  }
  __syncthreads();
  if (t < 256) hist[t] = 0u;   // ready for next pass / next iteration
}

// ---------- parallel select: w = alpha if bits > T; ties appended ----------
__global__ void wsel_kernel(const float* __restrict__ alpha, unsigned int* __restrict__ state,
                            float* __restrict__ wfin, int* __restrict__ tielist) {
  int e = blockIdx.x * blockDim.x + threadIdx.x;
  if (e >= EE) return;
  float av = alpha[e];
  unsigned int u = __float_as_uint(av);
  unsigned int T = state[2];
  float w = 0.f;
  if (u > T) w = av;
  else if (u == T) {
    unsigned int p = atomicAdd(state + 4, 1u);
    tielist[p] = e;
  }
  wfin[e] = w;
}

// tie-break: lowest edge index first (replicates jax.lax.top_k ordering)
__global__ void tiefix_kernel(const float* __restrict__ alpha, const unsigned int* __restrict__ state,
                              const int* __restrict__ tielist, float* __restrict__ wfin) {
  unsigned int need = state[3];
  unsigned int cnt = state[4];
  for (unsigned int t = threadIdx.x; t < cnt; t += blockDim.x) {
    int e = tielist[t];
    unsigned int rank = 0;
    for (unsigned int j = 0; j < cnt; j++) rank += (tielist[j] < e) ? 1u : 0u;
    if (rank < need) wfin[e] = alpha[e];
  }
}

// ---------- gather-reduce update by dst (CSR), upd = sum(w*msg) + x ----------
__global__ __launch_bounds__(256) void update_kernel(const int* __restrict__ esrc,
                                                     const int* __restrict__ rix,
                                                     const unsigned int* __restrict__ rowptr,
                                                     const int* __restrict__ csre,
                                                     const float* __restrict__ x,
                                                     const float* __restrict__ relflat,
                                                     const float* __restrict__ wfin,
                                                     float* __restrict__ upd) {
  int wave = threadIdx.x >> 6;
  int lane = threadIdx.x & 63;
  for (int n = blockIdx.x * 4 + wave; n < NN; n += gridDim.x * 4) {
    unsigned int p0 = rowptr[n], p1 = rowptr[n + 1];
    float2 acc = ((const float2*)(x + (size_t)n * ROW))[lane];
    for (unsigned int p = p0; p < p1; p++) {
      int e = csre[p];
      float w = wfin[e];
      if (w == 0.f) continue;
      int src = esrc[e], r = rix[e];
      float2 xv = ((const float2*)(x + (size_t)src * ROW))[lane];
      float2 rv = ((const float2*)(relflat + r * ROW))[lane];
      acc.x += w * (xv.x + rv.x);
      acc.y += w * (xv.y + rv.y);
    }
    ((float2*)(upd + (size_t)n * ROW))[lane] = acc;
  }
}

// ---------- readout (init only): racc = sum over nodes of x ----------
__global__ void readout_kernel(const float* __restrict__ x, float* __restrict__ racc) {
  int j = threadIdx.x;  // 0..127
  float acc = 0.f;
  for (int n = blockIdx.x; n < NN; n += gridDim.x) acc += x[(size_t)n * ROW + j];
  atomicAdd(racc + j, acc);
}

__global__ void trt_kernel(const float* __restrict__ racc, const float* __restrict__ tr_w,
                           const float* __restrict__ tr_b, float* __restrict__ trt) {
  int t = threadIdx.x;  // 0..127
  int b = t >> 6, f = t & 63;
  const float invN = 1.0f / (float)NN;
  float s = tr_b[f];
#pragma unroll
  for (int g = 0; g < FF; g++) s += (racc[b * FF + g] * invN) * tr_w[f * FF + g];
  trt[t] = s;
}

// ---------- per-node linear + LN + ELU + residual + next-iter racc/nodewa ----------
__global__ __launch_bounds__(256) void node_kernel(const float* __restrict__ upd,
                                                   const float* __restrict__ layer_w,
                                                   const float* __restrict__ layer_b,
                                                   const float* __restrict__ trt,
                                                   const float* __restrict__ ln_g,
                                                   const float* __restrict__ ln_b,
                                                   float* __restrict__ x,
                                                   const float* __restrict__ wa_next,
                                                   float* __restrict__ nodewa,
                                                   float* __restrict__ racc_next) {
  // weights, natural [f][c] layout, quad-XOR swizzle for conflict-free ds_read_b128
  __shared__ float lw[FF * ROW];   // 32 KB
  __shared__ float racc_sh[ROW];
  int tid = threadIdx.x;
  for (int t = tid; t < FF * ROW; t += 256) {
    int f = t >> 7, c = t & 127;
    int q = c >> 2, j = c & 3;
    lw[(f << 7) + (((q ^ (f & 7)) << 2) | j)] = layer_w[t];
  }
  if (tid < ROW) racc_sh[tid] = 0.f;
  __syncthreads();
  int wave = tid >> 6, lane = tid & 63;
  float lb = layer_b[lane];
  float t0 = trt[lane] + lb;
  float t1 = trt[64 + lane] + lb;
  float g_ = ln_g[lane], bta = ln_b[lane];
  float wn0 = wa_next[lane], wn1 = wa_next[64 + lane];
  float ra0 = 0.f, ra1 = 0.f;
  const float* lwf = lw + (lane << 7);
  int swz = (lane & 7) << 2;
  for (int n = blockIdx.x * 4 + wave; n < NN; n += gridDim.x * 4) {
    const float* xr = x + (size_t)n * ROW;
    const float* ur = upd + (size_t)n * ROW;
    float x0 = xr[lane], x1 = xr[64 + lane];
    float acc0 = t0, acc1 = t1;
#pragma unroll
    for (int q = 0; q < 16; q++) {
      float4 w = *(const float4*)(lwf + ((q << 2) ^ swz));
      float4 a0 = *(const float4*)(xr + (q << 2));
      float4 a1 = *(const float4*)(xr + 64 + (q << 2));
      acc0 += a0.x * w.x + a0.y * w.y + a0.z * w.z + a0.w * w.w;
      acc1 += a1.x * w.x + a1.y * w.y + a1.z * w.z + a1.w * w.w;
    }
#pragma unroll
    for (int q = 16; q < 32; q++) {
      float4 w = *(const float4*)(lwf + ((q << 2) ^ swz));
      float4 a0 = *(const float4*)(ur + ((q - 16) << 2));
      float4 a1 = *(const float4*)(ur + 64 + ((q - 16) << 2));
      acc0 += a0.x * w.x + a0.y * w.y + a0.z * w.z + a0.w * w.w;
      acc1 += a1.x * w.x + a1.y * w.y + a1.z * w.z + a1.w * w.w;
    }
    float s0 = acc0, q0 = acc0 * acc0, s1 = acc1, q1 = acc1 * acc1;
#pragma unroll
    for (int off = 32; off > 0; off >>= 1) {
      s0 += __shfl_xor(s0, off, 64);
      q0 += __shfl_xor(q0, off, 64);
      s1 += __shfl_xor(s1, off, 64);
      q1 += __shfl_xor(q1, off, 64);
    }
    const float invF = 1.0f / (float)FF;
    float mu0 = s0 * invF, mu1 = s1 * invF;
    float var0 = q0 * invF - mu0 * mu0;
    float var1 = q1 * invF - mu1 * mu1;
    float r0 = 1.0f / sqrtf(var0 + LN_EPS);
    float r1 = 1.0f / sqrtf(var1 + LN_EPS);
    float o0 = (acc0 - mu0) * r0 * g_ + bta;
    float o1 = (acc1 - mu1) * r1 * g_ + bta;
    float h0 = o0 > 0.f ? o0 : expm1f(o0);
    float h1 = o1 > 0.f ? o1 : expm1f(o1);
    float y0 = h0 + x0, y1 = h1 + x1;
    x[(size_t)n * ROW + lane] = y0;
    x[(size_t)n * ROW + 64 + lane] = y1;
    ra0 += y0;
    ra1 += y1;
    // nodewa for next iteration
    float nw = y0 * wn0 + y1 * wn1;
#pragma unroll
    for (int off = 32; off > 0; off >>= 1) nw += __shfl_xor(nw, off, 64);
    if (lane == 0) nodewa[n] = nw;
  }
  atomicAdd(&racc_sh[lane], ra0);
  atomicAdd(&racc_sh[64 + lane], ra1);
  __syncthreads();
  if (tid < ROW) atomicAdd(racc_next + tid, racc_sh[tid]);
}

extern "C" void kernel_launch(void* const* d_in, const int* in_sizes, int n_in,
                              void* d_out, int out_size, void* d_ws, size_t ws_size,
                              hipStream_t stream) {
  const int* ei = (const int*)d_in[0];
  const int* esrc = ei;
  const int* edst = ei + EE;
  const int* rix = (const int*)d_in[1];
  const float* boundary = (const float*)d_in[2];
  const float* query = (const float*)d_in[3];
  const float* rel_w = (const float*)d_in[4];
  const float* rel_b = (const float*)d_in[5];
  const float* layer_w = (const float*)d_in[6];
  const float* layer_b = (const float*)d_in[7];
  const float* tr_w = (const float*)d_in[8];
  const float* tr_b = (const float*)d_in[9];
  const float* Wm = (const float*)d_in[10];
  const float* av = (const float*)d_in[11];
  const float* ln_g = (const float*)d_in[12];
  const float* ln_b = (const float*)d_in[13];
  float* x = (float*)d_out;

  char* ws = (char*)d_ws;
  size_t off = 0;
  auto allocf = [&](size_t n) -> float* {
    float* p = (float*)(ws + off);
    off += ((n * 4 + 255) / 256) * 256;
    return p;
  };
  auto allocu = [&](size_t n) -> unsigned int* {
    unsigned int* p = (unsigned int*)(ws + off);
    off += ((n * 4 + 255) / 256) * 256;
    return p;
  };
  float* relflat = allocf(4096);
  float* wa4 = allocf(512);
  float* bufA = allocf(EE);        // alpha
  float* bufB = allocf(EE);        // exv, then wfin
  float* denom = allocf(NN);
  float* upd = allocf((size_t)NN * ROW);
  float* racc0 = allocf(128);
  float* racc1 = allocf(128);
  float* trt = allocf(128);
  float* relwa = allocf(32);
  float* nodewa = allocf(NN);
  unsigned int* segmax = allocu(NN);
  unsigned int* hist = allocu(256);
  unsigned int* state = allocu(8);
  unsigned int* deg = allocu(NN);
  unsigned int* rowptr = allocu(NN + 1);
  unsigned int* rowfill = allocu(NN);
  int* csre = (int*)allocu(EE);
  int* tielist = (int*)allocu(EE);
  float* rbuf[2] = {racc0, racc1};

  hipMemcpyAsync(x, boundary, (size_t)NN * ROW * 4, hipMemcpyDeviceToDevice, stream);
  hipMemsetAsync(hist, 0, 256 * 4, stream);
  hipMemsetAsync(deg, 0, NN * 4, stream);
  hipMemsetAsync(racc0, 0, 128 * 4, stream);
  precompute_kernel<<<16, 256, 0, stream>>>(query, rel_w, rel_b, Wm, av, relflat, wa4);

  // CSR by dst (edge_index is constant for this launch)
  degcnt_kernel<<<EE / 256, 256, 0, stream>>>(edst, deg);
  scan_kernel<<<1, 1024, 0, stream>>>(deg, rowptr, rowfill);
  fill_kernel<<<EE / 256, 256, 0, stream>>>(edst, rowfill, csre);

  // iter-0 readout sum and nodewa
  readout_kernel<<<256, 128, 0, stream>>>(x, racc0);
  nodewa_kernel<<<1250, 256, 0, stream>>>(x, wa4, nodewa);

  for (int it = 0; it < 4; it++) {
    float* rcur = rbuf[it & 1];
    float* rnxt = rbuf[(it + 1) & 1];
    hipMemsetAsync(segmax, 0, NN * 4, stream);
    hipMemsetAsync(denom, 0, NN * 4, stream);
    hipMemsetAsync(rnxt, 0, 128 * 4, stream);
    iterinit_kernel<<<1, 128, 0, stream>>>(state, relflat, wa4 + it * 128, relwa);

    segmax_kernel<<<EE / 256, 256, 0, stream>>>(esrc, rix, nodewa, relwa, segmax);
    ex_kernel<<<EE / 256, 256, 0, stream>>>(esrc, rix, nodewa, relwa, segmax, bufB, denom);

    hist0_kernel<<<320, 256, 0, stream>>>(esrc, bufB, denom, bufA, hist);  // bufA = alpha
    select_kernel<<<1, 256, 0, stream>>>(state, hist, 24);
    for (int shift = 16; shift >= 0; shift -= 8) {
      hist_kernel<<<320, 256, 0, stream>>>(bufA, state, hist, shift);
      select_kernel<<<1, 256, 0, stream>>>(state, hist, shift);
    }
    wsel_kernel<<<EE / 256, 256, 0, stream>>>(bufA, state, bufB, tielist);  // bufB = w
    tiefix_kernel<<<1, 256, 0, stream>>>(bufA, state, tielist, bufB);

    update_kernel<<<1250, 256, 0, stream>>>(esrc, rix, rowptr, csre, x, relflat, bufB, upd);

    trt_kernel<<<1, 128, 0, stream>>>(rcur, tr_w, tr_b, trt);
    node_kernel<<<1250, 256, 0, stream>>>(upd, layer_w, layer_b, trt, ln_g, ln_b, x,
                                          wa4 + (it < 3 ? it + 1 : 3) * 128, nodewa, rnxt);
  }
}

// Round 4
// 1263.413 us; speedup vs baseline: 1.9043x; 1.0566x over previous
//
#include <hip/hip_runtime.h>
#include <stdint.h>

#define NN 20000
#define EE 320000
#define FF 64
#define ROW 128              // B*F
#define KTOP 160000
#define NEG_SLOPE 0.2f
#define LN_EPS 1e-5f
#define TCAP 65536

// ---------- precompute: rel table [4096] and wa[4][128] ----------
__global__ void precompute_kernel(const float* __restrict__ query,
                                  const float* __restrict__ rel_w,
                                  const float* __restrict__ rel_b,
                                  const float* __restrict__ W,
                                  const float* __restrict__ a,
                                  float* __restrict__ relflat,
                                  float* __restrict__ wa4) {
  int t = blockIdx.x * blockDim.x + threadIdx.x;
  if (t < 4096) {
    int bq = t >> 11, c = t & 2047;
    const float* q = query + bq * FF;
    const float* w = rel_w + (size_t)c * FF;
    float s = rel_b[c];
#pragma unroll
    for (int f = 0; f < FF; f++) s += q[f] * w[f];
    relflat[t] = s;
  }
  if (t < 512) {
    int i = t >> 7, j = t & 127;
    const float* av = a + i * FF;
    const float* w = W + (size_t)j * FF;
    float s = 0.f;
#pragma unroll
    for (int f = 0; f < FF; f++) s += w[f] * av[f];
    wa4[t] = s;
  }
}

// ---------- CSR builds (once per launch) ----------
__global__ void degcnt_kernel(const int* __restrict__ esrc, const int* __restrict__ edst,
                              unsigned int* __restrict__ deg_s, unsigned int* __restrict__ deg_d) {
  int e = blockIdx.x * blockDim.x + threadIdx.x;
  if (e < EE) {
    atomicAdd(deg_s + esrc[e], 1u);
    atomicAdd(deg_d + edst[e], 1u);
  }
}

__global__ void scan_kernel(const unsigned int* __restrict__ deg,
                            unsigned int* __restrict__ rowptr,
                            unsigned int* __restrict__ rowfill) {
  __shared__ unsigned int sh[1024];
  int t = threadIdx.x;
  const int PER = 20;  // 1024*20 >= NN
  unsigned int loc[PER];
  unsigned int sum = 0;
  int base = t * PER;
#pragma unroll
  for (int i = 0; i < PER; i++) {
    int n = base + i;
    unsigned int d = (n < NN) ? deg[n] : 0u;
    loc[i] = sum;
    sum += d;
  }
  sh[t] = sum;
  __syncthreads();
  for (int o = 1; o < 1024; o <<= 1) {
    unsigned int v = (t >= o) ? sh[t - o] : 0u;
    __syncthreads();
    sh[t] += v;
    __syncthreads();
  }
  unsigned int excl = sh[t] - sum;
#pragma unroll
  for (int i = 0; i < PER; i++) {
    int n = base + i;
    if (n < NN) {
      unsigned int rp = excl + loc[i];
      rowptr[n] = rp;
      rowfill[n] = rp;
    }
  }
  if (t == 1023) rowptr[NN] = EE;
}

// fill both CSRs; src entries packed as e | (r<<19)
__global__ void fill_kernel(const int* __restrict__ esrc, const int* __restrict__ edst,
                            const int* __restrict__ rix,
                            unsigned int* __restrict__ rowfill_s, unsigned int* __restrict__ rowfill_d,
                            unsigned int* __restrict__ cspack_s, int* __restrict__ csre_d) {
  int e = blockIdx.x * blockDim.x + threadIdx.x;
  if (e < EE) {
    unsigned int r = (unsigned int)rix[e];
    unsigned int ss = atomicAdd(rowfill_s + esrc[e], 1u);
    cspack_s[ss] = (unsigned int)e | (r << 19);
    unsigned int sd = atomicAdd(rowfill_d + edst[e], 1u);
    csre_d[sd] = e;
  }
}

// packed_d[p] = src | (r<<20) in dst-CSR order
__global__ void gatherd_kernel(const int* __restrict__ csre_d, const int* __restrict__ esrc,
                               const int* __restrict__ rix, unsigned int* __restrict__ packed_d) {
  int p = blockIdx.x * blockDim.x + threadIdx.x;
  if (p < EE) {
    int e = csre_d[p];
    packed_d[p] = (unsigned int)esrc[e] | ((unsigned int)rix[e] << 20);
  }
}

// ---------- init: racc0 and nodewa ----------
__global__ void readout_kernel(const float* __restrict__ x, float* __restrict__ racc) {
  int j = threadIdx.x;  // 0..127
  float acc = 0.f;
  for (int n = blockIdx.x; n < NN; n += gridDim.x) acc += x[(size_t)n * ROW + j];
  atomicAdd(racc + j, acc);
}

__global__ void nodewa_kernel(const float* __restrict__ x, const float* __restrict__ wa,
                              float* __restrict__ nodewa) {
  int wave = threadIdx.x >> 6, lane = threadIdx.x & 63;
  float w0 = wa[lane], w1 = wa[64 + lane];
  for (int n = blockIdx.x * 4 + wave; n < NN; n += gridDim.x * 4) {
    float s = x[(size_t)n * ROW + lane] * w0 + x[(size_t)n * ROW + 64 + lane] * w1;
#pragma unroll
    for (int off = 32; off > 0; off >>= 1) s += __shfl_xor(s, off, 64);
    if (lane == 0) nodewa[n] = s;
  }
}

// ---------- per-src softmax + alpha + top-8 hist, no atomics on N arrays ----------
// state: [0]=prefix [1]=krem [2]=T [3]=need [4]=tiecnt [5]=candA_cnt [6]=cand2_cnt
__global__ __launch_bounds__(256) void alpha_csr_kernel(
    const unsigned int* __restrict__ rowptr_s, const unsigned int* __restrict__ cspack_s,
    const float* __restrict__ nodewa, const float* __restrict__ relflat,
    const float* __restrict__ wa, float* __restrict__ alpha,
    unsigned int* __restrict__ hist, unsigned int* __restrict__ state) {
  __shared__ float relwa_sh[32];
  __shared__ unsigned int h[256];
  int t = threadIdx.x;
  if (t >= 32) h[t - 32] = 0u;          // 224 of 256
  if (t < 32) { h[224 + t] = 0u; }
  if (t < 32) {
    float s = 0.f;
    const float4* rf = (const float4*)(relflat + t * ROW);
    const float4* wf = (const float4*)wa;
#pragma unroll 8
    for (int j = 0; j < 32; j++) {
      float4 r4 = rf[j], w4 = wf[j];
      s += r4.x * w4.x + r4.y * w4.y + r4.z * w4.z + r4.w * w4.w;
    }
    relwa_sh[t] = s;
  }
  if (blockIdx.x == 0 && t == 255) { state[0] = 0u; state[1] = KTOP; }
  __syncthreads();
  int n = blockIdx.x * 256 + t;
  if (n < NN) {
    unsigned int p0 = rowptr_s[n], p1 = rowptr_s[n + 1];
    float nw = nodewa[n];
    float denom = 0.f;
    for (unsigned int p = p0; p < p1; p++) {
      unsigned int cs = cspack_s[p];
      float v = nw + relwa_sh[cs >> 19];
      v = v > 0.f ? v : NEG_SLOPE * v;
      denom += expf(v);
    }
    float inv = 1.0f / denom;
    for (unsigned int p = p0; p < p1; p++) {
      unsigned int cs = cspack_s[p];
      float v = nw + relwa_sh[cs >> 19];
      v = v > 0.f ? v : NEG_SLOPE * v;
      float av = expf(v) * inv;
      alpha[cs & 0x7FFFFu] = av;
      atomicAdd(&h[__float_as_uint(av) >> 24], 1u);
    }
  }
  __syncthreads();
  if (t < 256) {
    unsigned int c = h[t];
    if (c) atomicAdd(hist + t, c);
  }
}

__global__ void select_kernel(unsigned int* __restrict__ state, unsigned int* __restrict__ hist, int shift) {
  __shared__ unsigned int sh[256];
  int t = threadIdx.x;
  if (t < 256) sh[t] = hist[t];
  __syncthreads();
  if (t == 0) {
    unsigned int krem = state[1];
    unsigned int cum = 0;
    int bin = 255;
    for (; bin > 0; bin--) {
      unsigned int c = sh[bin];
      if (cum + c >= krem) break;
      cum += c;
    }
    unsigned int pfx = (shift == 24) ? (unsigned)bin : ((state[0] << 8) | (unsigned)bin);
    state[0] = pfx;
    state[1] = krem - cum;
    if (shift == 24) state[5] = 0u;
    if (shift == 16) state[6] = 0u;
    if (shift == 0) { state[2] = pfx; state[3] = krem - cum; state[4] = 0u; }
  }
  __syncthreads();
  if (t < 256) hist[t] = 0u;
}

__device__ __forceinline__ int wave_append(unsigned int* ctr, bool pred) {
  int lane = threadIdx.x & 63;
  unsigned long long m = __ballot(pred);
  if (m == 0ULL) return -1;
  int leader = __ffsll((unsigned long long)m) - 1;
  int base = 0;
  if (lane == leader) base = (int)atomicAdd(ctr, (unsigned int)__popcll(m));
  base = __shfl(base, leader, 64);
  if (!pred) return -1;
  unsigned long long below = m & ((1ULL << lane) - 1ULL);
  return base + (int)__popcll(below);
}

// pass 2: full-E, match top-8 prefix -> hist bits 23..16 + compact candidates
__global__ void histB_kernel(const float* __restrict__ alpha, unsigned int* __restrict__ state,
                             unsigned int* __restrict__ hist, int* __restrict__ candA) {
  __shared__ unsigned int h[256];
  int t = threadIdx.x;
  h[t] = 0u;
  __syncthreads();
  unsigned int pfx = state[0];
  int e = blockIdx.x * 256 + t;
  bool match = false;
  unsigned int u = 0;
  if (e < EE) {
    u = __float_as_uint(alpha[e]);
    match = (u >> 24) == pfx;
  }
  if (match) atomicAdd(&h[(u >> 16) & 255u], 1u);
  int pos = wave_append(state + 5, match);
  if (match) candA[pos] = e;
  __syncthreads();
  unsigned int c = h[t];
  if (c) atomicAdd(hist + t, c);
}

// pass 3: over candA, match top-16 -> hist bits 15..8 + compact cand2
__global__ void histC_kernel(const float* __restrict__ alpha, unsigned int* __restrict__ state,
                             unsigned int* __restrict__ hist, const int* __restrict__ candA,
                             int* __restrict__ cand2) {
  __shared__ unsigned int h[256];
  int t = threadIdx.x;
  h[t] = 0u;
  __syncthreads();
  unsigned int pfx = state[0];
  unsigned int cnt = state[5];
  for (unsigned int i = blockIdx.x * 256 + t; ; i += gridDim.x * 256) {
    bool active = i < cnt;
    if (__ballot(active) == 0ULL) break;
    bool match = false;
    int e = 0;
    unsigned int u = 0;
    if (active) {
      e = candA[i];
      u = __float_as_uint(alpha[e]);
      match = (u >> 16) == pfx;
    }
    if (match) atomicAdd(&h[(u >> 8) & 255u], 1u);
    int pos = wave_append(state + 6, match);
    if (match) cand2[pos] = e;
  }
  __syncthreads();
  unsigned int c = h[t];
  if (c) atomicAdd(hist + t, c);
}

// pass 4: over cand2, match top-24 -> hist bits 7..0
__global__ void histD_kernel(const float* __restrict__ alpha, const unsigned int* __restrict__ state,
                             unsigned int* __restrict__ hist, const int* __restrict__ cand2) {
  __shared__ unsigned int h[256];
  int t = threadIdx.x;
  h[t] = 0u;
  __syncthreads();
  unsigned int pfx = state[0];
  unsigned int cnt = state[6];
  for (unsigned int i = blockIdx.x * 256 + t; ; i += gridDim.x * 256) {
    bool active = i < cnt;
    if (__ballot(active) == 0ULL) break;
    if (active) {
      unsigned int u = __float_as_uint(alpha[cand2[i]]);
      if ((u >> 8) == pfx) atomicAdd(&h[u & 255u], 1u);
    }
  }
  __syncthreads();
  unsigned int c = h[t];
  if (c) atomicAdd(hist + t, c);
}

// w-select in dst-CSR order; ties appended with (e, p)
__global__ void wsel_kernel(const float* __restrict__ alpha, const int* __restrict__ csre_d,
                            unsigned int* __restrict__ state, float* __restrict__ wfin_d,
                            int* __restrict__ tie_e, int* __restrict__ tie_p) {
  int p = blockIdx.x * blockDim.x + threadIdx.x;
  if (p >= EE) return;
  int e = csre_d[p];
  float av = alpha[e];
  unsigned int u = __float_as_uint(av);
  unsigned int T = state[2];
  float w = (u > T) ? av : 0.f;
  wfin_d[p] = w;
  bool tie = (u == T);
  int pos = wave_append(state + 4, tie);
  if (tie && pos < TCAP) { tie_e[pos] = e; tie_p[pos] = p; }
}

__global__ void tiefix_kernel(const unsigned int* __restrict__ state, const int* __restrict__ tie_e,
                              const int* __restrict__ tie_p, float* __restrict__ wfin_d) {
  unsigned int need = state[3];
  unsigned int cnt = state[4];
  if (cnt > TCAP) cnt = TCAP;
  float tv = __uint_as_float(state[2]);
  for (unsigned int t = threadIdx.x; t < cnt; t += blockDim.x) {
    int e = tie_e[t];
    unsigned int rank = 0;
    for (unsigned int j = 0; j < cnt; j++) rank += (tie_e[j] < e) ? 1u : 0u;
    if (rank < need) wfin_d[tie_p[t]] = tv;
  }
}

// ---------- gather-reduce update: 4 edges x 16 lanes per wave ----------
__global__ __launch_bounds__(256) void update_kernel(const unsigned int* __restrict__ rowptr_d,
                                                     const unsigned int* __restrict__ packed_d,
                                                     const float* __restrict__ wfin_d,
                                                     const float* __restrict__ x,
                                                     const float* __restrict__ relflat,
                                                     float* __restrict__ upd,
                                                     float* __restrict__ racc_next) {
  __shared__ float relf[32 * 132];
  int t = threadIdx.x;
  if (blockIdx.x == 0 && t < 128) racc_next[t] = 0.f;
#pragma unroll
  for (int i = 0; i < 4; i++) {
    int q = t + i * 256;                 // float4 idx 0..1023
    int r = q >> 5, kq = q & 31;
    float4 v = ((const float4*)relflat)[q];
    *(float4*)(relf + r * 132 + kq * 4) = v;
  }
  __syncthreads();
  int wave = t >> 6, lane = t & 63;
  int g = lane >> 4, l = lane & 15;
  int n = blockIdx.x * 4 + wave;
  if (n >= NN) return;
  unsigned int p0 = rowptr_d[n], p1 = rowptr_d[n + 1];
  float4 A0 = {0.f, 0.f, 0.f, 0.f}, A1 = {0.f, 0.f, 0.f, 0.f};
  for (unsigned int base = p0 + g; base < p1; base += 4) {
    float w = wfin_d[base];
    if (w == 0.f) continue;
    unsigned int up = packed_d[base];
    unsigned int src = up & 0xFFFFFu;
    unsigned int r = up >> 20;
    const float* xr = x + (size_t)src * ROW + l * 8;
    const float* rr = relf + r * 132 + l * 8;
    float4 xv0 = *(const float4*)xr;
    float4 xv1 = *(const float4*)(xr + 4);
    float4 rv0 = *(const float4*)rr;
    float4 rv1 = *(const float4*)(rr + 4);
    A0.x += w * (xv0.x + rv0.x); A0.y += w * (xv0.y + rv0.y);
    A0.z += w * (xv0.z + rv0.z); A0.w += w * (xv0.w + rv0.w);
    A1.x += w * (xv1.x + rv1.x); A1.y += w * (xv1.y + rv1.y);
    A1.z += w * (xv1.z + rv1.z); A1.w += w * (xv1.w + rv1.w);
  }
#pragma unroll
  for (int off = 16; off <= 32; off <<= 1) {
    A0.x += __shfl_xor(A0.x, off, 64); A0.y += __shfl_xor(A0.y, off, 64);
    A0.z += __shfl_xor(A0.z, off, 64); A0.w += __shfl_xor(A0.w, off, 64);
    A1.x += __shfl_xor(A1.x, off, 64); A1.y += __shfl_xor(A1.y, off, 64);
    A1.z += __shfl_xor(A1.z, off, 64); A1.w += __shfl_xor(A1.w, off, 64);
  }
  if (g == 0) {
    const float* xn = x + (size_t)n * ROW + l * 8;
    float4 xs0 = *(const float4*)xn;
    float4 xs1 = *(const float4*)(xn + 4);
    float4 o0 = {A0.x + xs0.x, A0.y + xs0.y, A0.z + xs0.z, A0.w + xs0.w};
    float4 o1 = {A1.x + xs1.x, A1.y + xs1.y, A1.z + xs1.z, A1.w + xs1.w};
    float* on = upd + (size_t)n * ROW + l * 8;
    *(float4*)on = o0;
    *(float4*)(on + 4) = o1;
  }
}

// ---------- node GEMM: [64 rows x 128] @ [128 x 64] + trt + LN + ELU + residual ----------
__global__ __launch_bounds__(256) void node_gemm_kernel(const float* __restrict__ upd,
                                                        const float* __restrict__ layer_w,
                                                        const float* __restrict__ layer_b,
                                                        const float* __restrict__ racc_cur,
                                                        const float* __restrict__ tr_w,
                                                        const float* __restrict__ tr_b,
                                                        const float* __restrict__ ln_g,
                                                        const float* __restrict__ ln_b,
                                                        float* __restrict__ x,
                                                        const float* __restrict__ wa_next,
                                                        float* __restrict__ nodewa,
                                                        float* __restrict__ racc_next) {
  __shared__ float As[64 * 132];
  __shared__ float Ws[64 * 132];
  __shared__ float trt_sh[128];
  __shared__ float racc_sh[128];
  __shared__ float nodewa_sh[32];
  int t = threadIdx.x;
  int n0 = blockIdx.x * 32;
  // per-block trt (readout linear) with layer_b folded in
  if (t < 128) {
    int b = t >> 6, f = t & 63;
    const float invN = 1.0f / (float)NN;
    float s = tr_b[f] + layer_b[f];
    const float* rr = racc_cur + b * 64;
    const float* tw = tr_w + f * 64;
#pragma unroll 16
    for (int gg = 0; gg < 64; gg++) s += rr[gg] * invN * tw[gg];
    trt_sh[t] = s;
    racc_sh[t] = 0.f;
  }
  if (t < 32) nodewa_sh[t] = 0.f;
  // stage A = [x | upd] rows, stride 132
#pragma unroll
  for (int i = 0; i < 4; i++) {
    int v = t + i * 256;                  // 0..1023 float4s
    int nl = v >> 5, i4 = v & 31;
    int b = i4 >> 4, kq = i4 & 15;
    int m = nl * 2 + b;
    float4 xv = ((const float4*)x)[n0 * 32 + v];
    *(float4*)(As + m * 132 + kq * 4) = xv;
  }
#pragma unroll
  for (int i = 0; i < 4; i++) {
    int v = t + i * 256;
    int nl = v >> 5, i4 = v & 31;
    int b = i4 >> 4, kq = i4 & 15;
    int m = nl * 2 + b;
    float4 uv = ((const float4*)upd)[n0 * 32 + v];
    *(float4*)(As + m * 132 + 64 + kq * 4) = uv;
  }
  // stage W swizzled: quad q of row f at position q ^ ((f>>2)&7)
#pragma unroll
  for (int i = 0; i < 8; i++) {
    int Q = t + i * 256;                  // 0..2047
    int f = Q >> 5, q = Q & 31;
    float4 wv = ((const float4*)layer_w)[Q];
    *(float4*)(Ws + f * 132 + ((q ^ ((f >> 2) & 7)) << 2)) = wv;
  }
  __syncthreads();
  int tx = t & 15, ty = t >> 4;
  float acc[4][4] = {};
  const float* Abase = As + (ty * 4) * 132;
  const float* Wbase = Ws + (tx * 4) * 132;
  int wswz = tx & 7;
#pragma unroll 4
  for (int kq = 0; kq < 32; kq++) {
    float4 a0 = *(const float4*)(Abase + 0 * 132 + kq * 4);
    float4 a1 = *(const float4*)(Abase + 1 * 132 + kq * 4);
    float4 a2 = *(const float4*)(Abase + 2 * 132 + kq * 4);
    float4 a3 = *(const float4*)(Abase + 3 * 132 + kq * 4);
    int wq = (kq ^ wswz) << 2;
    float4 w0 = *(const float4*)(Wbase + 0 * 132 + wq);
    float4 w1 = *(const float4*)(Wbase + 1 * 132 + wq);
    float4 w2 = *(const float4*)(Wbase + 2 * 132 + wq);
    float4 w3 = *(const float4*)(Wbase + 3 * 132 + wq);
#define DOT4(A, W) (A.x * W.x + A.y * W.y + A.z * W.z + A.w * W.w)
    acc[0][0] += DOT4(a0, w0); acc[0][1] += DOT4(a0, w1); acc[0][2] += DOT4(a0, w2); acc[0][3] += DOT4(a0, w3);
    acc[1][0] += DOT4(a1, w0); acc[1][1] += DOT4(a1, w1); acc[1][2] += DOT4(a1, w2); acc[1][3] += DOT4(a1, w3);
    acc[2][0] += DOT4(a2, w0); acc[2][1] += DOT4(a2, w1); acc[2][2] += DOT4(a2, w2); acc[2][3] += DOT4(a2, w3);
    acc[3][0] += DOT4(a3, w0); acc[3][1] += DOT4(a3, w1); acc[3][2] += DOT4(a3, w2); acc[3][3] += DOT4(a3, w3);
#undef DOT4
  }
  // add trt (+layer_b); rows m = ty*4+r, b = r&1
#pragma unroll
  for (int r = 0; r < 4; r++) {
    const float* tp = trt_sh + ((r & 1) << 6) + tx * 4;
#pragma unroll
    for (int c = 0; c < 4; c++) acc[r][c] += tp[c];
  }
  // LN stats over 64 f: reduce across 16 tx lanes
  float s[4], qq[4];
#pragma unroll
  for (int r = 0; r < 4; r++) {
    s[r] = acc[r][0] + acc[r][1] + acc[r][2] + acc[r][3];
    qq[r] = acc[r][0] * acc[r][0] + acc[r][1] * acc[r][1] + acc[r][2] * acc[r][2] + acc[r][3] * acc[r][3];
  }
#pragma unroll
  for (int off = 1; off < 16; off <<= 1) {
#pragma unroll
    for (int r = 0; r < 4; r++) {
      s[r] += __shfl_xor(s[r], off, 64);
      qq[r] += __shfl_xor(qq[r], off, 64);
    }
  }
  float4 g4 = ((const float4*)ln_g)[tx];
  float4 b4 = ((const float4*)ln_b)[tx];
  float4 wn = ((const float4*)wa_next)[tx];        // b=0 cols
  float4 wn1 = ((const float4*)wa_next)[16 + tx];  // b=1 cols
  const float invF = 1.0f / (float)FF;
  float nwc[2] = {0.f, 0.f};  // per local node (ty*2, ty*2+1)
#pragma unroll
  for (int r = 0; r < 4; r++) {
    float mu = s[r] * invF;
    float var = qq[r] * invF - mu * mu;
    float rstd = 1.0f / sqrtf(var + LN_EPS);
    int m = ty * 4 + r;
    int nl = m >> 1, b = m & 1;
    // residual x from global (still old values)
    float4 xo = ((const float4*)x)[(n0 + nl) * 32 + b * 16 + tx];
    float o0 = (acc[r][0] - mu) * rstd * g4.x + b4.x;
    float o1 = (acc[r][1] - mu) * rstd * g4.y + b4.y;
    float o2 = (acc[r][2] - mu) * rstd * g4.z + b4.z;
    float o3 = (acc[r][3] - mu) * rstd * g4.w + b4.w;
    float4 y;
    y.x = (o0 > 0.f ? o0 : expm1f(o0)) + xo.x;
    y.y = (o1 > 0.f ? o1 : expm1f(o1)) + xo.y;
    y.z = (o2 > 0.f ? o2 : expm1f(o2)) + xo.z;
    y.w = (o3 > 0.f ? o3 : expm1f(o3)) + xo.w;
    ((float4*)x)[(n0 + nl) * 32 + b * 16 + tx] = y;
    // racc accumulation
    float* rs = racc_sh + (b << 6) + tx * 4;
    atomicAdd(rs + 0, y.x); atomicAdd(rs + 1, y.y);
    atomicAdd(rs + 2, y.z); atomicAdd(rs + 3, y.w);
    // nodewa contribution
    float4 w = b ? wn1 : wn;
    nwc[r >> 1] += y.x * w.x + y.y * w.y + y.z * w.z + y.w * w.w;
  }
  atomicAdd(&nodewa_sh[ty * 2 + 0], nwc[0]);
  atomicAdd(&nodewa_sh[ty * 2 + 1], nwc[1]);
  __syncthreads();
  if (t < 128) atomicAdd(racc_next + t, racc_sh[t]);
  if (t < 32) nodewa[n0 + t] = nodewa_sh[t];
}

extern "C" void kernel_launch(void* const* d_in, const int* in_sizes, int n_in,
                              void* d_out, int out_size, void* d_ws, size_t ws_size,
                              hipStream_t stream) {
  const int* ei = (const int*)d_in[0];
  const int* esrc = ei;
  const int* edst = ei + EE;
  const int* rix = (const int*)d_in[1];
  const float* boundary = (const float*)d_in[2];
  const float* query = (const float*)d_in[3];
  const float* rel_w = (const float*)d_in[4];
  const float* rel_b = (const float*)d_in[5];
  const float* layer_w = (const float*)d_in[6];
  const float* layer_b = (const float*)d_in[7];
  const float* tr_w = (const float*)d_in[8];
  const float* tr_b = (const float*)d_in[9];
  const float* Wm = (const float*)d_in[10];
  const float* av = (const float*)d_in[11];
  const float* ln_g = (const float*)d_in[12];
  const float* ln_b = (const float*)d_in[13];
  float* x = (float*)d_out;

  char* ws = (char*)d_ws;
  size_t off = 0;
  auto allocf = [&](size_t n) -> float* {
    float* p = (float*)(ws + off);
    off += ((n * 4 + 255) / 256) * 256;
    return p;
  };
  auto allocu = [&](size_t n) -> unsigned int* {
    unsigned int* p = (unsigned int*)(ws + off);
    off += ((n * 4 + 255) / 256) * 256;
    return p;
  };
  float* relflat = allocf(4096);
  float* wa4 = allocf(512);
  float* alpha = allocf(EE);
  float* wfin_d = allocf(EE);
  float* upd = allocf((size_t)NN * ROW);
  float* racc0 = allocf(128);
  float* racc1 = allocf(128);
  float* nodewa = allocf(NN);
  unsigned int* hist = allocu(256);
  unsigned int* state = allocu(8);
  unsigned int* deg_s = allocu(NN);
  unsigned int* deg_d = allocu(NN);
  unsigned int* rowptr_s = allocu(NN + 1);
  unsigned int* rowptr_d = allocu(NN + 1);
  unsigned int* rowfill_s = allocu(NN);
  unsigned int* rowfill_d = allocu(NN);
  unsigned int* cspack_s = allocu(EE);
  int* csre_d = (int*)allocu(EE);
  unsigned int* packed_d = allocu(EE);
  int* candA = (int*)allocu(EE);
  int* cand2 = (int*)allocu(EE);
  int* tie_e = (int*)allocu(TCAP);
  int* tie_p = (int*)allocu(TCAP);
  float* rbuf[2] = {racc0, racc1};

  hipMemcpyAsync(x, boundary, (size_t)NN * ROW * 4, hipMemcpyDeviceToDevice, stream);
  hipMemsetAsync(hist, 0, 256 * 4, stream);
  hipMemsetAsync(deg_s, 0, NN * 4, stream);
  hipMemsetAsync(deg_d, 0, NN * 4, stream);
  hipMemsetAsync(racc0, 0, 128 * 4, stream);
  precompute_kernel<<<16, 256, 0, stream>>>(query, rel_w, rel_b, Wm, av, relflat, wa4);

  // CSR builds (edge_index constant for this launch)
  degcnt_kernel<<<EE / 256, 256, 0, stream>>>(esrc, edst, deg_s, deg_d);
  scan_kernel<<<1, 1024, 0, stream>>>(deg_s, rowptr_s, rowfill_s);
  scan_kernel<<<1, 1024, 0, stream>>>(deg_d, rowptr_d, rowfill_d);
  fill_kernel<<<EE / 256, 256, 0, stream>>>(esrc, edst, rix, rowfill_s, rowfill_d, cspack_s, csre_d);
  gatherd_kernel<<<EE / 256, 256, 0, stream>>>(csre_d, esrc, rix, packed_d);

  // iter-0 readout sum and nodewa
  readout_kernel<<<256, 128, 0, stream>>>(x, racc0);
  nodewa_kernel<<<1250, 256, 0, stream>>>(x, wa4, nodewa);

  for (int it = 0; it < 4; it++) {
    float* rcur = rbuf[it & 1];
    float* rnxt = rbuf[(it + 1) & 1];
    const float* wa_it = wa4 + it * 128;
    const float* wa_nx = wa4 + (it < 3 ? it + 1 : 3) * 128;

    alpha_csr_kernel<<<(NN + 255) / 256, 256, 0, stream>>>(rowptr_s, cspack_s, nodewa,
                                                           relflat, wa_it, alpha, hist, state);
    select_kernel<<<1, 256, 0, stream>>>(state, hist, 24);
    histB_kernel<<<EE / 256, 256, 0, stream>>>(alpha, state, hist, candA);
    select_kernel<<<1, 256, 0, stream>>>(state, hist, 16);
    histC_kernel<<<320, 256, 0, stream>>>(alpha, state, hist, candA, cand2);
    select_kernel<<<1, 256, 0, stream>>>(state, hist, 8);
    histD_kernel<<<320, 256, 0, stream>>>(alpha, state, hist, cand2);
    select_kernel<<<1, 256, 0, stream>>>(state, hist, 0);
    wsel_kernel<<<EE / 256, 256, 0, stream>>>(alpha, csre_d, state, wfin_d, tie_e, tie_p);
    tiefix_kernel<<<1, 256, 0, stream>>>(state, tie_e, tie_p, wfin_d);

    update_kernel<<<5000, 256, 0, stream>>>(rowptr_d, packed_d, wfin_d, x, relflat, upd, rnxt);
    node_gemm_kernel<<<625, 256, 0, stream>>>(upd, layer_w, layer_b, rcur, tr_w, tr_b,
                                              ln_g, ln_b, x, wa_nx, nodewa, rnxt);
  }
}